// Round 8
// baseline (40420.026 us; speedup 1.0000x reference)
//
#include <hip/hip_runtime.h>
#include <math.h>

#define SEQT 8192
#define HID  256
#define NTG  27
#define NEGV -10000.0f
#define START_TAG 25
#define STOP_TAG  26
#define POLL_LIM  (1 << 16)
#define GRID      256
#define NWORK     19          // 0..7 L0, 8..15 L1, 16..17 EM, 18 CRF
#define NHEAT     (GRID - NWORK)
#define HEAT_CAP  4000        // failure-path bound only; normal exit via flag
#define DYN_LDS   (84 * 1024) // forces 1 block/CU: workers get exclusive CUs

// ---------------- agent-scope (L3) communication primitives -----------------
__device__ __forceinline__ float l3_load_f(const float* p) {
  float v;
  asm volatile("global_load_dword %0, %1, off sc1\n\t"
               "s_waitcnt vmcnt(0)"
               : "=v"(v) : "v"(p) : "memory");
  return v;
}
__device__ __forceinline__ float4 l3_load_f4(const float* p) {
  float4 v;
  asm volatile("global_load_dwordx4 %0, %1, off sc1\n\t"
               "s_waitcnt vmcnt(0)"
               : "=v"(v) : "v"(p) : "memory");
  return v;
}
__device__ __forceinline__ void l3_load_16(const float* p, float4& a, float4& b,
                                           float4& c, float4& d) {
  asm volatile("global_load_dwordx4 %0, %4, off sc1\n\t"
               "global_load_dwordx4 %1, %4, off offset:16 sc1\n\t"
               "global_load_dwordx4 %2, %4, off offset:32 sc1\n\t"
               "global_load_dwordx4 %3, %4, off offset:48 sc1\n\t"
               "s_waitcnt vmcnt(0)"
               : "=&v"(a), "=&v"(b), "=&v"(c), "=&v"(d)
               : "v"(p) : "memory");
}
__device__ __forceinline__ void l3_load_16x2(const float* p, const float* q,
    float4& a0, float4& a1, float4& a2, float4& a3,
    float4& b0, float4& b1, float4& b2, float4& b3) {
  asm volatile("global_load_dwordx4 %0, %8, off sc1\n\t"
               "global_load_dwordx4 %1, %8, off offset:16 sc1\n\t"
               "global_load_dwordx4 %2, %8, off offset:32 sc1\n\t"
               "global_load_dwordx4 %3, %8, off offset:48 sc1\n\t"
               "global_load_dwordx4 %4, %9, off sc1\n\t"
               "global_load_dwordx4 %5, %9, off offset:16 sc1\n\t"
               "global_load_dwordx4 %6, %9, off offset:32 sc1\n\t"
               "global_load_dwordx4 %7, %9, off offset:48 sc1\n\t"
               "s_waitcnt vmcnt(0)"
               : "=&v"(a0), "=&v"(a1), "=&v"(a2), "=&v"(a3),
                 "=&v"(b0), "=&v"(b1), "=&v"(b2), "=&v"(b3)
               : "v"(p), "v"(q) : "memory");
}
__device__ __forceinline__ void l3_store_f(float* p, float v) {
  asm volatile("global_store_dword %0, %1, off sc1" :: "v"(p), "v"(v) : "memory");
}
__device__ __forceinline__ void l3_store_i(int* p, int v) {
  asm volatile("global_store_dword %0, %1, off sc1" :: "v"(p), "v"(v) : "memory");
}
__device__ __forceinline__ int l3_load_i(const int* p) {
  int v;
  asm volatile("global_load_dword %0, %1, off sc1\n\t"
               "s_waitcnt vmcnt(0)"
               : "=v"(v) : "v"(p) : "memory");
  return v;
}
__device__ __forceinline__ int chk4(float4 v) {
  return (fabsf(v.x) < 2.0f) & (fabsf(v.y) < 2.0f) &
         (fabsf(v.z) < 2.0f) & (fabsf(v.w) < 2.0f);
}
__device__ __forceinline__ float sigm(float x) { return 1.0f / (1.0f + __expf(-x)); }
__device__ __forceinline__ float tanh_f(float x) {
  x = fminf(15.0f, fmaxf(-15.0f, x));
  float e = __expf(-2.0f * x);
  return (1.0f - e) / (1.0f + e);
}
// wave-uniform tight-spin poll of 16 contiguous floats per lane; sticky dead
__device__ __forceinline__ void poll16(const float* p, float4& A, float4& B,
                                       float4& C, float4& D, int& dead) {
  l3_load_16(p, A, B, C, D);
  if (dead) return;
  int c = 0;
  while (!__all(chk4(A) & chk4(B) & chk4(C) & chk4(D))) {
    if (++c >= POLL_LIM) { dead = 1; return; }
    l3_load_16(p, A, B, C, D);
  }
}

// ======================= layer-0 LSTM: 64 barrier-free waves ================
// Wave owns 4 cells (cb..cb+3). lane=(g=lane>>4 gate, r=lane&15).
// h-cols per lane: [16r,16r+16) contiguous (4 x dwordx4). x-cols: {16m+r}.
__device__ void l0_run(int wid, const int* sent, const float* emb,
                       const float* w_ih0, const float* w_hh0,
                       const float* b_ih0, const float* b_hh0, float* h0hist) {
  const int lane = threadIdx.x & 63;
  const int g = lane >> 4, r = lane & 15;
  const int cb = wid * 4;

  float wh[4][16], wx[4][7];
#pragma unroll
  for (int j = 0; j < 4; ++j) {
    const int row = g * 256 + cb + j;
#pragma unroll
    for (int k = 0; k < 16; ++k) wh[j][k] = w_hh0[row * 256 + r * 16 + k];
#pragma unroll
    for (int m = 0; m < 7; ++m) {
      int c = m * 16 + r;
      wx[j][m] = (c < 100) ? w_ih0[row * 100 + c] : 0.0f;
    }
  }
  float bI = 0, bF = 0, bG = 0, bO = 0, cst = 0.0f;
  if (lane < 4) {
    int cell = cb + lane;
    bI = b_ih0[cell]       + b_hh0[cell];
    bF = b_ih0[256 + cell] + b_hh0[256 + cell];
    bG = b_ih0[512 + cell] + b_hh0[512 + cell];
    bO = b_ih0[768 + cell] + b_hh0[768 + cell];
  }
  int dead = 0;

  // prologue: x_0 in regs, sent[1] prefetched
  float xv[7];
  {
    const float* xrow = emb + (size_t)sent[0] * 100;
#pragma unroll
    for (int m = 0; m < 7; ++m) {
      int c = m * 16 + r;
      xv[m] = (c < 100) ? xrow[c] : 0.0f;
    }
  }
  int snext = sent[1];

  for (int t = 0; t < SEQT; ++t) {
    float4 A, B, C, D;
    if (t > 0) {
      poll16(h0hist + (size_t)(t - 1) * HID + r * 16, A, B, C, D, dead);
    } else {
      A = B = C = D = make_float4(0.f, 0.f, 0.f, 0.f);
    }
    float hv[16] = {A.x,A.y,A.z,A.w, B.x,B.y,B.z,B.w,
                    C.x,C.y,C.z,C.w, D.x,D.y,D.z,D.w};
    float acc[4] = {0.f, 0.f, 0.f, 0.f};
#pragma unroll
    for (int m = 0; m < 7; ++m)
#pragma unroll
      for (int j = 0; j < 4; ++j) acc[j] = fmaf(wx[j][m], xv[m], acc[j]);
#pragma unroll
    for (int k = 0; k < 16; ++k)
#pragma unroll
      for (int j = 0; j < 4; ++j) acc[j] = fmaf(wh[j][k], hv[k], acc[j]);

    // software-pipelined x prefetch for t+1 (hides emb gather latency)
    float xn[7]; int s2 = 0;
    if (t + 1 < SEQT) {
      const float* xr = emb + (size_t)snext * 100;
#pragma unroll
      for (int m = 0; m < 7; ++m) {
        int c = m * 16 + r;
        xn[m] = (c < 100) ? xr[c] : 0.0f;
      }
      if (t + 2 < SEQT) s2 = sent[t + 2];
    } else {
#pragma unroll
      for (int m = 0; m < 7; ++m) xn[m] = 0.0f;
    }

#pragma unroll
    for (int d = 1; d < 16; d <<= 1)
#pragma unroll
      for (int j = 0; j < 4; ++j) acc[j] += __shfl_xor(acc[j], d);
    float v = (r == 0) ? acc[0] : (r == 1) ? acc[1] : (r == 2) ? acc[2] : acc[3];
    float gI = __shfl(v, lane);
    float gF = __shfl(v, 16 + lane);
    float gG = __shfl(v, 32 + lane);
    float gO = __shfl(v, 48 + lane);
    if (lane < 4) {
      float gi = sigm(gI + bI), gf = sigm(gF + bF);
      float gg = tanh_f(gG + bG), go = sigm(gO + bO);
      cst = gf * cst + gi * gg;
      if (!dead) l3_store_f(h0hist + (size_t)t * HID + cb + lane, go * tanh_f(cst));
    }
#pragma unroll
    for (int m = 0; m < 7; ++m) xv[m] = xn[m];
    snext = s2;
  }
}

// ======================= layer-1 LSTM: 64 barrier-free waves ================
__device__ void l1_run(int wid, const float* w_ih1, const float* w_hh1,
                       const float* b_ih1, const float* b_hh1,
                       const float* h0hist, float* h1hist) {
  const int lane = threadIdx.x & 63;
  const int g = lane >> 4, r = lane & 15;
  const int cb = wid * 4;

  float wx[4][16], wh[4][16];
#pragma unroll
  for (int j = 0; j < 4; ++j) {
    const int row = g * 256 + cb + j;
#pragma unroll
    for (int k = 0; k < 16; ++k) {
      wx[j][k] = w_ih1[row * 256 + r * 16 + k];
      wh[j][k] = w_hh1[row * 256 + r * 16 + k];
    }
  }
  float bI = 0, bF = 0, bG = 0, bO = 0, cst = 0.0f;
  if (lane < 4) {
    int cell = cb + lane;
    bI = b_ih1[cell]       + b_hh1[cell];
    bF = b_ih1[256 + cell] + b_hh1[256 + cell];
    bG = b_ih1[512 + cell] + b_hh1[512 + cell];
    bO = b_ih1[768 + cell] + b_hh1[768 + cell];
  }
  int dead = 0;

  for (int t = 0; t < SEQT; ++t) {
    float4 X0, X1, X2, X3, H0, H1, H2, H3;
    const float* hp0 = h0hist + (size_t)t * HID + r * 16;
    const float* hp1 = h1hist + (size_t)(t - 1) * HID + r * 16;
    if (t > 0) {
      l3_load_16x2(hp0, hp1, X0, X1, X2, X3, H0, H1, H2, H3);  // both in flight
    } else {
      l3_load_16(hp0, X0, X1, X2, X3);
      H0 = H1 = H2 = H3 = make_float4(0.f, 0.f, 0.f, 0.f);
    }
    if (!dead) {
      int c = 0;
      while (!__all(chk4(X0) & chk4(X1) & chk4(X2) & chk4(X3))) {
        if (++c >= POLL_LIM) { dead = 1; break; }
        l3_load_16(hp0, X0, X1, X2, X3);
      }
    }
    float x0[16] = {X0.x,X0.y,X0.z,X0.w, X1.x,X1.y,X1.z,X1.w,
                    X2.x,X2.y,X2.z,X2.w, X3.x,X3.y,X3.z,X3.w};
    float acc[4] = {0.f, 0.f, 0.f, 0.f};
#pragma unroll
    for (int k = 0; k < 16; ++k)
#pragma unroll
      for (int j = 0; j < 4; ++j) acc[j] = fmaf(wx[j][k], x0[k], acc[j]);
    if (t > 0 && !dead) {               // x-FMAs hid part of the h1 wait
      int c = 0;
      while (!__all(chk4(H0) & chk4(H1) & chk4(H2) & chk4(H3))) {
        if (++c >= POLL_LIM) { dead = 1; break; }
        l3_load_16(hp1, H0, H1, H2, H3);
      }
    }
    float hv[16] = {H0.x,H0.y,H0.z,H0.w, H1.x,H1.y,H1.z,H1.w,
                    H2.x,H2.y,H2.z,H2.w, H3.x,H3.y,H3.z,H3.w};
#pragma unroll
    for (int k = 0; k < 16; ++k)
#pragma unroll
      for (int j = 0; j < 4; ++j) acc[j] = fmaf(wh[j][k], hv[k], acc[j]);
#pragma unroll
    for (int d = 1; d < 16; d <<= 1)
#pragma unroll
      for (int j = 0; j < 4; ++j) acc[j] += __shfl_xor(acc[j], d);
    float v = (r == 0) ? acc[0] : (r == 1) ? acc[1] : (r == 2) ? acc[2] : acc[3];
    float gI = __shfl(v, lane);
    float gF = __shfl(v, 16 + lane);
    float gG = __shfl(v, 32 + lane);
    float gO = __shfl(v, 48 + lane);
    if (lane < 4) {
      float gi = sigm(gI + bI), gf = sigm(gF + bF);
      float gg = tanh_f(gG + bG), go = sigm(gO + bO);
      cst = gf * cst + gi * gg;
      if (!dead) l3_store_f(h1hist + (size_t)t * HID + cb + lane, go * tanh_f(cst));
    }
  }
}

// ============ emission team: 2 blocks x 8 waves, pairs over t mod 8 =========
__device__ void em_run(int sub, int wv, const float* w_lin, const float* b_lin,
                       const float* h1hist, float* scores) {
  const int lane = threadIdx.x & 63;
  const int pair = sub * 4 + (wv >> 1);
  const int half = wv & 1;
  const int tbase = half ? 14 : 0;
  const int ntg   = half ? 13 : 14;

  float wl[14][4];
#pragma unroll
  for (int i = 0; i < 14; ++i) {
    int tg = tbase + ((i < ntg) ? i : (ntg - 1));
#pragma unroll
    for (int j = 0; j < 4; ++j) wl[i][j] = w_lin[tg * 256 + 4 * lane + j];
  }
  const float bl = b_lin[tbase + ((lane < ntg) ? lane : 0)];
  int dead = 0;

  for (int t = pair; t < SEQT; t += 8) {
    const float* hp = h1hist + (size_t)t * HID + 4 * lane;
    float4 v = l3_load_f4(hp);
    if (!dead) {
      int c = 0;
      while (!__all(chk4(v))) {
        if (++c >= POLL_LIM) { dead = 1; break; }
        v = l3_load_f4(hp);
      }
    }
    float acc[14];
#pragma unroll
    for (int i = 0; i < 14; ++i)
      acc[i] = wl[i][0] * v.x + wl[i][1] * v.y + wl[i][2] * v.z + wl[i][3] * v.w;
#pragma unroll
    for (int d = 1; d < 64; d <<= 1)
#pragma unroll
      for (int i = 0; i < 14; ++i) acc[i] += __shfl_xor(acc[i], d);
    float outv = acc[0];
#pragma unroll
    for (int i = 1; i < 14; ++i) if (lane == i) outv = acc[i];
    if (lane < ntg && !dead) l3_store_f(scores + t * 32 + tbase + lane, outv + bl);
  }
}

// ============== CRF: wave 0 runs viterbi; whole block backtraces ============
__device__ void crf_run(const int* amask, const float* trans,
                        const float* scores, unsigned char* bpb, float* out,
                        int* flags) {
  __shared__ int btag[129];
  __shared__ int maps[128][NTG];
  __shared__ int blockdead;
  const int tid = threadIdx.x;

  if ((tid >> 6) == 0) {
    const int lane = tid & 63;
    const int tau = lane & 31, half = lane >> 5;
    const bool act = (tau < NTG);
    const int tq = act ? tau : NTG - 1;

    float tc[14];
#pragma unroll
    for (int k = 0; k < 14; ++k) {
      int f = half ? (13 + k) : k;
      tc[k] = trans[f * NTG + tq];
    }
    const float tstop = trans[tq * NTG + STOP_TAG];
    float vreg = (act && tau == START_TAG) ? 0.0f : NEGV;
    int dead = 0;

    for (int t = 0; t < SEQT; ++t) {
      float e = 0.0f;
      if (act) e = l3_load_f(scores + t * 32 + tau);
      if (!dead) {
        int c = 0;
        while (!__all(act ? (fabsf(e) < 1000.0f) : 1)) {
          if (++c >= POLL_LIM) { dead = 1; break; }
          if (act) e = l3_load_f(scores + t * 32 + tau);
        }
      }
      const int m = amask[t];
      float best = -3.0e38f; int barg = 0;
#pragma unroll
      for (int k = 0; k < 14; ++k) {  // hi half re-covers f=13: harmless for max
        int f = half ? (13 + k) : k;
        float vf = __shfl(vreg, half ? (45 + k) : k);
        float c = vf + tc[k];
        if (c > best) { best = c; barg = f; }  // ascending f + strict > = first-max
      }
      float ob = __shfl_xor(best, 32);
      int   oa = __shfl_xor(barg, 32);
      bool take = half ? (ob >= best) : (ob > best);  // ties -> lower f (lo half)
      if (take) { best = ob; barg = oa; }
      float vn = best + e;
      vreg = m ? vn : vreg;
      int bpv = m ? barg : tau;
      if (act && half == 0 && !dead) bpb[(t << 5) + tau] = (unsigned char)bpv;
    }
    float tv = (act && half == 0) ? (vreg + tstop) : -3.0e38f;
    int   ti = (act && half == 0) ? tau : 64;
#pragma unroll
    for (int off = 32; off >= 1; off >>= 1) {
      float ov = __shfl_xor(tv, off);
      int   oi = __shfl_xor(ti, off);
      if ((ov > tv) || (ov == tv && oi < ti)) { tv = ov; ti = oi; }
    }
    if (lane == 0) {
      blockdead = dead;
      if (!dead) { out[0] = tv; btag[128] = ti; }
    }
  }
  __syncthreads();
  if (blockdead) {                     // no garbage output; still free heaters
    if (tid < NHEAT) l3_store_i(flags + tid * 16, 1);
    return;
  }

  // per-64-step tag maps: 128 chunks x 27 end tags, 7 interleaved chains/thread
  {
    int bs[7], es[7], tg[7], nk = 0;
#pragma unroll
    for (int k = 0; k < 7; ++k) {
      int task = tid + k * 512;
      if (task < 128 * NTG) { bs[k] = task / NTG; es[k] = task % NTG; tg[k] = es[k]; nk = k + 1; }
      else { bs[k] = 0; es[k] = 0; tg[k] = 0; }
    }
    for (int i = 63; i >= 0; --i) {
#pragma unroll
      for (int k = 0; k < 7; ++k)
        if (k < nk) tg[k] = bpb[((bs[k] * 64 + i) << 5) + tg[k]];
    }
#pragma unroll
    for (int k = 0; k < 7; ++k) if (k < nk) maps[bs[k]][es[k]] = tg[k];
  }
  __syncthreads();

  if (tid == 0) {
    int e = btag[128];
    for (int b = 127; b >= 0; --b) { btag[b] = e; e = maps[b][e]; }
  }
  __syncthreads();

  if (tid < 128) {
    int b = tid, tag = btag[b];
    for (int i = 63; i >= 0; --i) {
      out[1 + b * 64 + i] = (float)tag;
      tag = bpb[((b * 64 + i) << 5) + tag];
    }
  }
  __syncthreads();
  if (tid < NHEAT) l3_store_i(flags + tid * 16, 1);   // release heaters
}

// ====== heater: clock boost, isolated CUs (1 block/CU via dyn LDS) ==========
__device__ void heat_run(int hb, const int* flags, const float* emb) {
  const int lane = threadIdx.x & 63;
  const int* myflag = flags + hb * 16;                // private 64B line
  float a = 1.0f + 1e-7f * (float)lane;
  float b = 0.99999988f;
  float c = 1.0f - 1e-7f * (float)lane;
  float acc = 0.0f;
  const float* ep = emb + (size_t)hb * 2048 + 4 * lane;
  for (int o = 0; o < HEAT_CAP; ++o) {
    if (l3_load_i(myflag)) break;                     // ~1 load / ~16k cycles
    if ((o & 15) == 0) {                              // light fabric activity
      float4 v = l3_load_f4(ep + (size_t)(o & 1023) * 16);
      acc += v.x;
    }
#pragma unroll 32
    for (int i = 0; i < 2048; ++i) {                  // 2 interleaved FMA chains
      a = fmaf(a, b, 1e-9f);
      c = fmaf(c, b, 1.1e-9f);
    }
    asm volatile("" :: "v"(a), "v"(c), "v"(acc));     // keep live, no DCE
  }
}

// ===========================================================================
__global__ __launch_bounds__(512, 1)
void lstm_crf_iso(const int* sent, const int* amask, const float* emb,
                  const float* w_ih0, const float* w_hh0,
                  const float* b_ih0, const float* b_hh0,
                  const float* w_ih1, const float* w_hh1,
                  const float* b_ih1, const float* b_hh1,
                  const float* w_lin, const float* b_lin, const float* trans,
                  float* h0hist, float* h1hist, float* scores,
                  unsigned char* bpb, int* flags, float* out) {
  extern __shared__ char dynpad[];     // occupancy limiter: 1 block/CU
  const int b = blockIdx.x;
  const int wv = threadIdx.x >> 6;
  if (b == 0x7fffffff) dynpad[0] = 1;  // unreachable; keeps dynpad referenced
  if (b < 8) {
    l0_run(b * 8 + wv, sent, emb, w_ih0, w_hh0, b_ih0, b_hh0, h0hist);
  } else if (b < 16) {
    l1_run((b - 8) * 8 + wv, w_ih1, w_hh1, b_ih1, b_hh1, h0hist, h1hist);
  } else if (b < 18) {
    em_run(b - 16, wv, w_lin, b_lin, h1hist, scores);
  } else if (b == 18) {
    crf_run(amask, trans, scores, bpb, out, flags);
  } else {
    heat_run(b - NWORK, flags, emb);
  }
}

extern "C" void kernel_launch(void* const* d_in, const int* in_sizes, int n_in,
                              void* d_out, int out_size, void* d_ws, size_t ws_size,
                              hipStream_t stream) {
  const int*   sent  = (const int*)d_in[0];
  const int*   amask = (const int*)d_in[1];
  const float* emb   = (const float*)d_in[2];
  const float* w_ih0 = (const float*)d_in[3];
  const float* w_hh0 = (const float*)d_in[4];
  const float* b_ih0 = (const float*)d_in[5];
  const float* b_hh0 = (const float*)d_in[6];
  const float* w_ih1 = (const float*)d_in[7];
  const float* w_hh1 = (const float*)d_in[8];
  const float* b_ih1 = (const float*)d_in[9];
  const float* b_hh1 = (const float*)d_in[10];
  const float* w_lin = (const float*)d_in[11];
  const float* b_lin = (const float*)d_in[12];
  const float* trans = (const float*)d_in[13];

  float* h0hist = (float*)d_ws;                                   // 8192*256 f32
  float* h1hist = h0hist + (size_t)SEQT * HID;                    // 8192*256 f32
  float* scores = h1hist + (size_t)SEQT * HID;                    // 8192*32  f32
  unsigned char* bpb = (unsigned char*)(scores + (size_t)SEQT * 32);  // 8192*32 B
  int*   flags = (int*)(bpb + (size_t)SEQT * 32);                 // 256 x 64B
  float* out   = (float*)d_out;

  // re-arm sentinel (0x7F7F7F7F = 3.39e38: fails |v|<2 and |v|<1000)
  (void)hipMemsetAsync(d_ws, 0x7F,
                       ((size_t)2 * SEQT * HID + (size_t)SEQT * 32) * sizeof(float),
                       stream);
  (void)hipMemsetAsync(flags, 0, (size_t)GRID * 64, stream);      // clear flags

  lstm_crf_iso<<<GRID, 512, DYN_LDS, stream>>>(
      sent, amask, emb, w_ih0, w_hh0, b_ih0, b_hh0,
      w_ih1, w_hh1, b_ih1, b_hh1, w_lin, b_lin, trans,
      h0hist, h1hist, scores, bpb, flags, out);
}

// Round 9
// 24230.011 us; speedup vs baseline: 1.6682x; 1.6682x over previous
//
#include <hip/hip_runtime.h>
#include <math.h>

#define SEQT 8192
#define HID  256
#define NTG  27
#define NEGV -10000.0f
#define START_TAG 25
#define STOP_TAG  26
#define POLL_LIM  (1 << 16)
#define SENT32    0x7F7F7F7Fu
#define GRID      19          // 0..7 L0, 8..15 L1, 16..17 EM, 18 CRF
#define RSTRIDE   ((size_t)SEQT * 128)   // u32 stride of one replica (bf16 rows)

// ---------------- agent-scope (L3) communication primitives -----------------
__device__ __forceinline__ float l3_load_f(const float* p) {
  float v;
  asm volatile("global_load_dword %0, %1, off sc1\n\t"
               "s_waitcnt vmcnt(0)"
               : "=v"(v) : "v"(p) : "memory");
  return v;
}
__device__ __forceinline__ uint2 l3_load_u2(const unsigned int* p) {
  uint2 v;
  asm volatile("global_load_dwordx2 %0, %1, off sc1\n\t"
               "s_waitcnt vmcnt(0)"
               : "=v"(v) : "v"(p) : "memory");
  return v;
}
__device__ __forceinline__ void l3_load_u2x2(const unsigned int* p,
                                             const unsigned int* q,
                                             uint2& a, uint2& b) {
  asm volatile("global_load_dwordx2 %0, %2, off sc1\n\t"
               "global_load_dwordx2 %1, %3, off sc1\n\t"
               "s_waitcnt vmcnt(0)"
               : "=&v"(a), "=&v"(b) : "v"(p), "v"(q) : "memory");
}
__device__ __forceinline__ void l3_store_f(float* p, float v) {
  asm volatile("global_store_dword %0, %1, off sc1" :: "v"(p), "v"(v) : "memory");
}
__device__ __forceinline__ void l3_store_u(unsigned int* p, unsigned int v) {
  asm volatile("global_store_dword %0, %1, off sc1" :: "v"(p), "v"(v) : "memory");
}
__device__ __forceinline__ float sigm(float x) { return 1.0f / (1.0f + __expf(-x)); }
__device__ __forceinline__ float tanh_f(float x) {
  x = fminf(15.0f, fmaxf(-15.0f, x));
  float e = __expf(-2.0f * x);
  return (1.0f - e) / (1.0f + e);
}
// bf16 pack/unpack (RNE pack; values finite, |h|<=1)
__device__ __forceinline__ float bf_lo(unsigned int u) {
  return __uint_as_float(u << 16);
}
__device__ __forceinline__ float bf_hi(unsigned int u) {
  return __uint_as_float(u & 0xFFFF0000u);
}
__device__ __forceinline__ unsigned int rne_bf16(float f) {
  unsigned int u = __float_as_uint(f);
  return (u + 0x7FFFu + ((u >> 16) & 1u)) >> 16;
}
__device__ __forceinline__ unsigned int pack_bf(float a, float b) {
  return rne_bf16(a) | (rne_bf16(b) << 16);
}

// ======================= layer-0 LSTM: 8 blocks x 8 waves ===================
// Block owns 32 cells; wave wv owns cells cb..cb+3 (cb = (blk*8+wv)*4).
// Wave 0 is the block's ONLY poller: spins on replica (blk&1) of h0[t-1]
// (lane polls 8B = 2 u32 of the 512B bf16 row), then LDS-broadcasts the raw
// u32s; one __syncthreads per step. Producers store each packed pair to BOTH
// replicas (fire-and-forget).
__device__ void l0_run(int blk, int wv, const int* sent, const float* emb,
                       const float* w_ih0, const float* w_hh0,
                       const float* b_ih0, const float* b_hh0,
                       unsigned int* h0rep) {
  __shared__ unsigned int lsh[2][128];
  __shared__ int sdead;
  const int lane = threadIdx.x & 63;
  const int g = lane >> 4, r = lane & 15;
  const int wid = blk * 8 + wv;
  const int cb = wid * 4;

  float wh[4][16], wx[4][7];
#pragma unroll
  for (int j = 0; j < 4; ++j) {
    const int row = g * 256 + cb + j;
#pragma unroll
    for (int k = 0; k < 16; ++k) wh[j][k] = w_hh0[row * 256 + r * 16 + k];
#pragma unroll
    for (int m = 0; m < 7; ++m) {
      int c = m * 16 + r;
      wx[j][m] = (c < 100) ? w_ih0[row * 100 + c] : 0.0f;
    }
  }
  float bI = 0, bF = 0, bG = 0, bO = 0, cst = 0.0f;
  if (lane < 4) {
    int cell = cb + lane;
    bI = b_ih0[cell]       + b_hh0[cell];
    bF = b_ih0[256 + cell] + b_hh0[256 + cell];
    bG = b_ih0[512 + cell] + b_hh0[512 + cell];
    bO = b_ih0[768 + cell] + b_hh0[768 + cell];
  }
  if (threadIdx.x == 0) sdead = 0;
  int dead = 0;

  // prologue: x_0 in regs, sent[1] prefetched
  float xv[7];
  {
    const float* xrow = emb + (size_t)sent[0] * 100;
#pragma unroll
    for (int m = 0; m < 7; ++m) {
      int c = m * 16 + r;
      xv[m] = (c < 100) ? xrow[c] : 0.0f;
    }
  }
  int snext = sent[1];
  const size_t repoff = (size_t)(blk & 1) * RSTRIDE;
  __syncthreads();

  for (int t = 0; t < SEQT; ++t) {
    if (wv == 0 && t > 0) {              // the block's single poller
      const unsigned int* pp = h0rep + repoff + (size_t)(t - 1) * 128 + 2 * lane;
      uint2 U = l3_load_u2(pp);
      if (!dead) {
        int c = 0;
        while (!__all((U.x != SENT32) & (U.y != SENT32))) {
          if (++c >= POLL_LIM) { if (lane == 0) sdead = 1; dead = 1; break; }
          U = l3_load_u2(pp);
        }
      }
      lsh[t & 1][2 * lane]     = U.x;
      lsh[t & 1][2 * lane + 1] = U.y;
    }
    __syncthreads();                     // one barrier per step
    if (sdead) dead = 1;

    float hv[16];
    if (t > 0) {
#pragma unroll
      for (int k = 0; k < 8; ++k) {
        unsigned int u = lsh[t & 1][8 * r + k];
        hv[2 * k]     = bf_lo(u);
        hv[2 * k + 1] = bf_hi(u);
      }
    } else {
#pragma unroll
      for (int k = 0; k < 16; ++k) hv[k] = 0.0f;
    }

    float acc[4] = {0.f, 0.f, 0.f, 0.f};
#pragma unroll
    for (int m = 0; m < 7; ++m)
#pragma unroll
      for (int j = 0; j < 4; ++j) acc[j] = fmaf(wx[j][m], xv[m], acc[j]);
#pragma unroll
    for (int k = 0; k < 16; ++k)
#pragma unroll
      for (int j = 0; j < 4; ++j) acc[j] = fmaf(wh[j][k], hv[k], acc[j]);

    // software-pipelined x prefetch for t+1
    float xn[7]; int s2 = 0;
    if (t + 1 < SEQT) {
      const float* xr = emb + (size_t)snext * 100;
#pragma unroll
      for (int m = 0; m < 7; ++m) {
        int c = m * 16 + r;
        xn[m] = (c < 100) ? xr[c] : 0.0f;
      }
      if (t + 2 < SEQT) s2 = sent[t + 2];
    } else {
#pragma unroll
      for (int m = 0; m < 7; ++m) xn[m] = 0.0f;
    }

#pragma unroll
    for (int d = 1; d < 16; d <<= 1)
#pragma unroll
      for (int j = 0; j < 4; ++j) acc[j] += __shfl_xor(acc[j], d);
    float v = (r == 0) ? acc[0] : (r == 1) ? acc[1] : (r == 2) ? acc[2] : acc[3];
    float gI = __shfl(v, lane);
    float gF = __shfl(v, 16 + lane);
    float gG = __shfl(v, 32 + lane);
    float gO = __shfl(v, 48 + lane);
    float hval = 0.0f;
    if (lane < 4) {
      float gi = sigm(gI + bI), gf = sigm(gF + bF);
      float gg = tanh_f(gG + bG), go = sigm(gO + bO);
      cst = gf * cst + gi * gg;
      hval = go * tanh_f(cst);
    }
    float h0v = __shfl(hval, 0), h1v = __shfl(hval, 1);
    float h2v = __shfl(hval, 2), h3v = __shfl(hval, 3);
    if (lane < 2 && !dead) {
      unsigned int u = (lane == 0) ? pack_bf(h0v, h1v) : pack_bf(h2v, h3v);
      unsigned int* d0 = h0rep + (size_t)t * 128 + wid * 2 + lane;
      l3_store_u(d0, u);                 // replica 0
      l3_store_u(d0 + RSTRIDE, u);       // replica 1
    }
#pragma unroll
    for (int m = 0; m < 7; ++m) xv[m] = xn[m];
    snext = s2;
  }
}

// ======================= layer-1 LSTM: 8 blocks x 8 waves ===================
// Poller (wave 0) spins jointly on h0rep[blk&1][t] and h1rep[blk&1][t-1],
// LDS-broadcasts both raw rows.
__device__ void l1_run(int blk, int wv, const float* w_ih1, const float* w_hh1,
                       const float* b_ih1, const float* b_hh1,
                       const unsigned int* h0rep, unsigned int* h1rep) {
  __shared__ unsigned int lsh0[2][128];
  __shared__ unsigned int lsh1[2][128];
  __shared__ int sdead;
  const int lane = threadIdx.x & 63;
  const int g = lane >> 4, r = lane & 15;
  const int wid = blk * 8 + wv;
  const int cb = wid * 4;

  float wx[4][16], wh[4][16];
#pragma unroll
  for (int j = 0; j < 4; ++j) {
    const int row = g * 256 + cb + j;
#pragma unroll
    for (int k = 0; k < 16; ++k) {
      wx[j][k] = w_ih1[row * 256 + r * 16 + k];
      wh[j][k] = w_hh1[row * 256 + r * 16 + k];
    }
  }
  float bI = 0, bF = 0, bG = 0, bO = 0, cst = 0.0f;
  if (lane < 4) {
    int cell = cb + lane;
    bI = b_ih1[cell]       + b_hh1[cell];
    bF = b_ih1[256 + cell] + b_hh1[256 + cell];
    bG = b_ih1[512 + cell] + b_hh1[512 + cell];
    bO = b_ih1[768 + cell] + b_hh1[768 + cell];
  }
  if (threadIdx.x == 0) sdead = 0;
  int dead = 0;
  const size_t repoff = (size_t)(blk & 1) * RSTRIDE;
  __syncthreads();

  for (int t = 0; t < SEQT; ++t) {
    if (wv == 0) {                       // single poller
      const unsigned int* p0 = h0rep + repoff + (size_t)t * 128 + 2 * lane;
      uint2 A, B;
      if (t > 0) {
        const unsigned int* p1 = h1rep + repoff + (size_t)(t - 1) * 128 + 2 * lane;
        l3_load_u2x2(p0, p1, A, B);
        if (!dead) {
          int c = 0;
          while (!__all((A.x != SENT32) & (A.y != SENT32) &
                        (B.x != SENT32) & (B.y != SENT32))) {
            if (++c >= POLL_LIM) { if (lane == 0) sdead = 1; dead = 1; break; }
            l3_load_u2x2(p0, p1, A, B);
          }
        }
        lsh1[t & 1][2 * lane]     = B.x;
        lsh1[t & 1][2 * lane + 1] = B.y;
      } else {
        A = l3_load_u2(p0);
        if (!dead) {
          int c = 0;
          while (!__all((A.x != SENT32) & (A.y != SENT32))) {
            if (++c >= POLL_LIM) { if (lane == 0) sdead = 1; dead = 1; break; }
            A = l3_load_u2(p0);
          }
        }
      }
      lsh0[t & 1][2 * lane]     = A.x;
      lsh0[t & 1][2 * lane + 1] = A.y;
    }
    __syncthreads();
    if (sdead) dead = 1;

    float x0[16], hv[16];
#pragma unroll
    for (int k = 0; k < 8; ++k) {
      unsigned int u = lsh0[t & 1][8 * r + k];
      x0[2 * k]     = bf_lo(u);
      x0[2 * k + 1] = bf_hi(u);
    }
    if (t > 0) {
#pragma unroll
      for (int k = 0; k < 8; ++k) {
        unsigned int u = lsh1[t & 1][8 * r + k];
        hv[2 * k]     = bf_lo(u);
        hv[2 * k + 1] = bf_hi(u);
      }
    } else {
#pragma unroll
      for (int k = 0; k < 16; ++k) hv[k] = 0.0f;
    }

    float acc[4] = {0.f, 0.f, 0.f, 0.f};
#pragma unroll
    for (int k = 0; k < 16; ++k)
#pragma unroll
      for (int j = 0; j < 4; ++j) acc[j] = fmaf(wx[j][k], x0[k], acc[j]);
#pragma unroll
    for (int k = 0; k < 16; ++k)
#pragma unroll
      for (int j = 0; j < 4; ++j) acc[j] = fmaf(wh[j][k], hv[k], acc[j]);
#pragma unroll
    for (int d = 1; d < 16; d <<= 1)
#pragma unroll
      for (int j = 0; j < 4; ++j) acc[j] += __shfl_xor(acc[j], d);
    float v = (r == 0) ? acc[0] : (r == 1) ? acc[1] : (r == 2) ? acc[2] : acc[3];
    float gI = __shfl(v, lane);
    float gF = __shfl(v, 16 + lane);
    float gG = __shfl(v, 32 + lane);
    float gO = __shfl(v, 48 + lane);
    float hval = 0.0f;
    if (lane < 4) {
      float gi = sigm(gI + bI), gf = sigm(gF + bF);
      float gg = tanh_f(gG + bG), go = sigm(gO + bO);
      cst = gf * cst + gi * gg;
      hval = go * tanh_f(cst);
    }
    float h0v = __shfl(hval, 0), h1v = __shfl(hval, 1);
    float h2v = __shfl(hval, 2), h3v = __shfl(hval, 3);
    if (lane < 2 && !dead) {
      unsigned int u = (lane == 0) ? pack_bf(h0v, h1v) : pack_bf(h2v, h3v);
      unsigned int* d0 = h1rep + (size_t)t * 128 + wid * 2 + lane;
      l3_store_u(d0, u);
      l3_store_u(d0 + RSTRIDE, u);
    }
  }
}

// ============ emission team: 2 blocks x 8 waves, pairs over t mod 8 =========
// Lane polls 2 u32 (4 bf16 cols 4*lane..4*lane+3) of h1 replica (t&1).
__device__ void em_run(int sub, int wv, const float* w_lin, const float* b_lin,
                       const unsigned int* h1rep, float* scores) {
  const int lane = threadIdx.x & 63;
  const int pair = sub * 4 + (wv >> 1);
  const int half = wv & 1;
  const int tbase = half ? 14 : 0;
  const int ntg   = half ? 13 : 14;

  float wl[14][4];
#pragma unroll
  for (int i = 0; i < 14; ++i) {
    int tg = tbase + ((i < ntg) ? i : (ntg - 1));
#pragma unroll
    for (int j = 0; j < 4; ++j) wl[i][j] = w_lin[tg * 256 + 4 * lane + j];
  }
  const float bl = b_lin[tbase + ((lane < ntg) ? lane : 0)];
  int dead = 0;

  for (int t = pair; t < SEQT; t += 8) {
    const unsigned int* hp = h1rep + (size_t)(t & 1) * RSTRIDE
                           + (size_t)t * 128 + 2 * lane;
    uint2 U = l3_load_u2(hp);
    if (!dead) {
      int c = 0;
      while (!__all((U.x != SENT32) & (U.y != SENT32))) {
        if (++c >= POLL_LIM) { dead = 1; break; }
        U = l3_load_u2(hp);
      }
    }
    float v0 = bf_lo(U.x), v1 = bf_hi(U.x), v2 = bf_lo(U.y), v3 = bf_hi(U.y);
    float acc[14];
#pragma unroll
    for (int i = 0; i < 14; ++i)
      acc[i] = wl[i][0] * v0 + wl[i][1] * v1 + wl[i][2] * v2 + wl[i][3] * v3;
#pragma unroll
    for (int d = 1; d < 64; d <<= 1)
#pragma unroll
      for (int i = 0; i < 14; ++i) acc[i] += __shfl_xor(acc[i], d);
    float outv = acc[0];
#pragma unroll
    for (int i = 1; i < 14; ++i) if (lane == i) outv = acc[i];
    if (lane < ntg && !dead) l3_store_f(scores + t * 32 + tbase + lane, outv + bl);
  }
}

// ============== CRF: wave 0 runs viterbi; whole block backtraces ============
__device__ void crf_run(const int* amask, const float* trans,
                        const float* scores, unsigned char* bpb, float* out) {
  __shared__ int btag[129];
  __shared__ int maps[128][NTG];
  __shared__ int blockdead;
  const int tid = threadIdx.x;

  if ((tid >> 6) == 0) {
    const int lane = tid & 63;
    const int tau = lane & 31, half = lane >> 5;
    const bool act = (tau < NTG);
    const int tq = act ? tau : NTG - 1;

    float tc[14];
#pragma unroll
    for (int k = 0; k < 14; ++k) {
      int f = half ? (13 + k) : k;
      tc[k] = trans[f * NTG + tq];
    }
    const float tstop = trans[tq * NTG + STOP_TAG];
    float vreg = (act && tau == START_TAG) ? 0.0f : NEGV;
    int dead = 0;

    for (int t = 0; t < SEQT; ++t) {
      float e = 0.0f;
      if (act) e = l3_load_f(scores + t * 32 + tau);
      if (!dead) {
        int c = 0;
        while (!__all(act ? (fabsf(e) < 1000.0f) : 1)) {
          if (++c >= POLL_LIM) { dead = 1; break; }
          if (act) e = l3_load_f(scores + t * 32 + tau);
        }
      }
      const int m = amask[t];
      float best = -3.0e38f; int barg = 0;
#pragma unroll
      for (int k = 0; k < 14; ++k) {  // hi half re-covers f=13: harmless for max
        int f = half ? (13 + k) : k;
        float vf = __shfl(vreg, half ? (45 + k) : k);
        float c = vf + tc[k];
        if (c > best) { best = c; barg = f; }  // ascending f + strict > = first-max
      }
      float ob = __shfl_xor(best, 32);
      int   oa = __shfl_xor(barg, 32);
      bool take = half ? (ob >= best) : (ob > best);  // ties -> lower f (lo half)
      if (take) { best = ob; barg = oa; }
      float vn = best + e;
      vreg = m ? vn : vreg;
      int bpv = m ? barg : tau;
      if (act && half == 0 && !dead) bpb[(t << 5) + tau] = (unsigned char)bpv;
    }
    float tv = (act && half == 0) ? (vreg + tstop) : -3.0e38f;
    int   ti = (act && half == 0) ? tau : 64;
#pragma unroll
    for (int off = 32; off >= 1; off >>= 1) {
      float ov = __shfl_xor(tv, off);
      int   oi = __shfl_xor(ti, off);
      if ((ov > tv) || (ov == tv && oi < ti)) { tv = ov; ti = oi; }
    }
    if (lane == 0) {
      blockdead = dead;
      if (!dead) { out[0] = tv; btag[128] = ti; }
    }
  }
  __syncthreads();
  if (blockdead) return;   // never write garbage into the output

  // per-64-step tag maps: 128 chunks x 27 end tags, 7 interleaved chains/thread
  {
    int bs[7], es[7], tg[7], nk = 0;
#pragma unroll
    for (int k = 0; k < 7; ++k) {
      int task = tid + k * 512;
      if (task < 128 * NTG) { bs[k] = task / NTG; es[k] = task % NTG; tg[k] = es[k]; nk = k + 1; }
      else { bs[k] = 0; es[k] = 0; tg[k] = 0; }
    }
    for (int i = 63; i >= 0; --i) {
#pragma unroll
      for (int k = 0; k < 7; ++k)
        if (k < nk) tg[k] = bpb[((bs[k] * 64 + i) << 5) + tg[k]];
    }
#pragma unroll
    for (int k = 0; k < 7; ++k) if (k < nk) maps[bs[k]][es[k]] = tg[k];
  }
  __syncthreads();

  if (tid == 0) {
    int e = btag[128];
    for (int b = 127; b >= 0; --b) { btag[b] = e; e = maps[b][e]; }
  }
  __syncthreads();

  if (tid < 128) {
    int b = tid, tag = btag[b];
    for (int i = 63; i >= 0; --i) {
      out[1 + b * 64 + i] = (float)tag;
      tag = bpb[((b * 64 + i) << 5) + tag];
    }
  }
}

// ===========================================================================
__global__ __launch_bounds__(512, 1)
void lstm_crf_rep(const int* sent, const int* amask, const float* emb,
                  const float* w_ih0, const float* w_hh0,
                  const float* b_ih0, const float* b_hh0,
                  const float* w_ih1, const float* w_hh1,
                  const float* b_ih1, const float* b_hh1,
                  const float* w_lin, const float* b_lin, const float* trans,
                  unsigned int* h0rep, unsigned int* h1rep, float* scores,
                  unsigned char* bpb, float* out) {
  const int b = blockIdx.x;
  const int wv = threadIdx.x >> 6;
  if (b < 8) {
    l0_run(b, wv, sent, emb, w_ih0, w_hh0, b_ih0, b_hh0, h0rep);
  } else if (b < 16) {
    l1_run(b - 8, wv, w_ih1, w_hh1, b_ih1, b_hh1, h0rep, h1rep);
  } else if (b < 18) {
    em_run(b - 16, wv, w_lin, b_lin, h1rep, scores);
  } else {
    crf_run(amask, trans, scores, bpb, out);
  }
}

extern "C" void kernel_launch(void* const* d_in, const int* in_sizes, int n_in,
                              void* d_out, int out_size, void* d_ws, size_t ws_size,
                              hipStream_t stream) {
  const int*   sent  = (const int*)d_in[0];
  const int*   amask = (const int*)d_in[1];
  const float* emb   = (const float*)d_in[2];
  const float* w_ih0 = (const float*)d_in[3];
  const float* w_hh0 = (const float*)d_in[4];
  const float* b_ih0 = (const float*)d_in[5];
  const float* b_hh0 = (const float*)d_in[6];
  const float* w_ih1 = (const float*)d_in[7];
  const float* w_hh1 = (const float*)d_in[8];
  const float* b_ih1 = (const float*)d_in[9];
  const float* b_hh1 = (const float*)d_in[10];
  const float* w_lin = (const float*)d_in[11];
  const float* b_lin = (const float*)d_in[12];
  const float* trans = (const float*)d_in[13];

  unsigned int* h0rep = (unsigned int*)d_ws;            // 2 replicas x 8192x128 u32 (bf16 rows)
  unsigned int* h1rep = h0rep + 2 * RSTRIDE;            // same
  float* scores = (float*)(h1rep + 2 * RSTRIDE);        // 8192*32 f32
  unsigned char* bpb = (unsigned char*)(scores + (size_t)SEQT * 32);  // 8192*32 B
  float* out = (float*)d_out;

  // re-arm sentinel (0x7F7F7F7F: impossible for packed |h|<=1 bf16 pairs and
  // for |score|<1000 f32) every call
  (void)hipMemsetAsync(d_ws, 0x7F,
                       (4 * RSTRIDE + (size_t)SEQT * 32) * sizeof(unsigned int),
                       stream);

  lstm_crf_rep<<<GRID, 512, 0, stream>>>(
      sent, amask, emb, w_ih0, w_hh0, b_ih0, b_hh0,
      w_ih1, w_hh1, b_ih1, b_hh1, w_lin, b_lin, trans,
      h0rep, h1rep, scores, bpb, out);
}